// Round 5
// baseline (946.842 us; speedup 1.0000x reference)
//
#include <hip/hip_runtime.h>
#include <math.h>

#define Bsz 16
#define Tt 24
#define Nn 256
#define Fp 6
#define Hh 64
#define PredL 12
#define Fw 4
#define G3 192
#define M1 32
#define TCHUNK 8
#define DEG2RAD 0.017453292519943295f
#define IDX2(t, b) ((t) * Bsz + (b))

// ---------------------------------------------------------------------------
// P0+PT merged: blocks 0..255 build Ac/As; block 256 repacks weights.
// ---------------------------------------------------------------------------
__global__ __launch_bounds__(256) void k_prep(
    const float* __restrict__ coords, const float* __restrict__ adj,
    const float* __restrict__ wgc2, const float* __restrict__ wih,
    const float* __restrict__ whh,  const float* __restrict__ wm1,
    const float* __restrict__ wm2,
    float* __restrict__ Ac, float* __restrict__ As,
    float* __restrict__ wgc2T, float* __restrict__ wm1T, float* __restrict__ wm2T,
    float4* __restrict__ wihP, float4* __restrict__ whhP) {
  int tid = threadIdx.x;
  if (blockIdx.x < Nn) {
    int i = blockIdx.x;
    int j = tid;
    float dx = coords[2 * j]     - coords[2 * i];
    float dy = coords[2 * j + 1] - coords[2 * i + 1];
    float ang = atan2f(dy, dx);
    float a = adj[i * Nn + j];
    Ac[i * Nn + j] = a * cosf(ang);
    As[i * Nn + j] = a * sinf(ang);
    return;
  }
  for (int idx = tid; idx < Hh * Hh; idx += 256) {
    int g = idx / Hh, k = idx % Hh;
    wgc2T[k * Hh + g] = wgc2[g * Hh + k];
  }
  for (int idx = tid; idx < M1 * Hh; idx += 256) {
    int m = idx / Hh, k = idx % Hh;
    wm1T[k * M1 + m] = wm1[m * Hh + k];
  }
  for (int idx = tid; idx < Fp * M1; idx += 256) {
    int f = idx / M1, m = idx % M1;
    wm2T[m * Fp + f] = wm2[f * M1 + m];
  }
  for (int idx = tid; idx < Hh * 64; idx += 256) {
    int k = idx >> 6, lane = idx & 63;
    wihP[idx] = make_float4(wih[(0 * 64 + lane) * Hh + k],
                            wih[(1 * 64 + lane) * Hh + k],
                            wih[(2 * 64 + lane) * Hh + k], 0.f);
    whhP[idx] = make_float4(whh[(0 * 64 + lane) * Hh + k],
                            whh[(1 * 64 + lane) * Hh + k],
                            whh[(2 * 64 + lane) * Hh + k], 0.f);
  }
}

// ---------------------------------------------------------------------------
// P1: degree normalizations for every (t,b,i).
// ---------------------------------------------------------------------------
__global__ __launch_bounds__(256) void k_deg(
    const float* __restrict__ hw, const float* __restrict__ Ac,
    const float* __restrict__ As,
    float* __restrict__ dbuf, float* __restrict__ ebuf) {
  int q  = blockIdx.x & 3;
  int tb = blockIdx.x >> 2;
  int t = tb / Bsz, b = tb % Bsz;
  float spd = hw[(b * Tt + t) * Fw + 2];
  float rad = hw[(b * Tt + t) * Fw + 1] * DEG2RAD;
  float cr = cosf(rad), sr = sinf(rad);
  int w = threadIdx.x >> 6, lane = threadIdx.x & 63;
  for (int m = 0; m < 16; ++m) {
    int i = q * 64 + w * 16 + m;
    float rs = 0.f, cs = 0.f;
#pragma unroll
    for (int c = 0; c < 4; ++c) {
      int j = lane + 64 * c;
      float val = spd * (Ac[i * Nn + j] * cr + As[i * Nn + j] * sr);
      rs += fmaxf(val, 0.f);
      cs += (j == i) ? fmaxf(val, 0.f) : fmaxf(-val, 0.f);
    }
#pragma unroll
    for (int off = 32; off; off >>= 1) {
      rs += __shfl_xor(rs, off);
      cs += __shfl_xor(cs, off);
    }
    if (lane == 0) {
      dbuf[IDX2(t, b) * Nn + i] = 1.f / (sqrtf(rs + 1.f) + 1e-6f);
      ebuf[IDX2(t, b) * Nn + i] = 1.f / (sqrtf(cs + 1.f) + 1e-6f);
    }
  }
}

// ---------------------------------------------------------------------------
// E1: batched encoder gconv1 over ALL t.
// ---------------------------------------------------------------------------
__global__ __launch_bounds__(256) void k_gconv1_enc(
    const float* __restrict__ hp, const float* __restrict__ hw,
    const float* __restrict__ Ac, const float* __restrict__ As,
    const float* __restrict__ dbuf,
    const float* __restrict__ wgc1, const float* __restrict__ bgc1,
    float* __restrict__ h1_all) {
  __shared__ float d_lds[Nn];
  __shared__ float x_lds[Nn * Fp];
  int ig = blockIdx.x & 15;
  int tb = blockIdx.x >> 4;
  int t = tb / Bsz, b = tb % Bsz;
  int i0 = ig * 16;
  int tid = threadIdx.x, w = tid >> 6, lane = tid & 63;
  float spd = hw[(b * Tt + t) * Fw + 2];
  float rad = hw[(b * Tt + t) * Fw + 1] * DEG2RAD;
  float cr = cosf(rad), sr = sinf(rad);
  d_lds[tid] = dbuf[IDX2(t, b) * Nn + tid];
  const float* xsrc = hp + (long)(b * Tt + t) * Nn * Fp;
#pragma unroll
  for (int c = 0; c < 6; ++c) x_lds[tid + 256 * c] = xsrc[tid + 256 * c];
  __syncthreads();
#pragma unroll
  for (int rr = 0; rr < 4; ++rr) {
    int i = i0 + w * 4 + rr;
    float acc[Fp] = {0.f, 0.f, 0.f, 0.f, 0.f, 0.f};
#pragma unroll
    for (int c = 0; c < 4; ++c) {
      int j = lane + 64 * c;
      float val = spd * (Ac[i * Nn + j] * cr + As[i * Nn + j] * sr);
      float wt = fmaxf(val, 0.f) * d_lds[j];
#pragma unroll
      for (int f = 0; f < Fp; ++f) acc[f] += wt * x_lds[j * Fp + f];
    }
#pragma unroll
    for (int f = 0; f < Fp; ++f) {
#pragma unroll
      for (int off = 32; off; off >>= 1) acc[f] += __shfl_xor(acc[f], off);
    }
    float di = d_lds[i];
    float y[Fp];
#pragma unroll
    for (int f = 0; f < Fp; ++f) y[f] = di * (acc[f] + di * x_lds[i * Fp + f]);
    float hv = bgc1[lane];
#pragma unroll
    for (int f = 0; f < Fp; ++f) hv += wgc1[lane * Fp + f] * y[f];
    h1_all[((long)IDX2(t, b) * Nn + i) * Hh + lane] = fmaxf(hv, 0.f);
  }
}

// ---------------------------------------------------------------------------
// E2: batched encoder gconv2 + W_gc2 transform over ALL t -> sf_all
// ---------------------------------------------------------------------------
__global__ __launch_bounds__(256) void k_gconv2_enc(
    const float* __restrict__ hw, const float* __restrict__ Ac,
    const float* __restrict__ As, const float* __restrict__ ebuf,
    const float* __restrict__ h1_all,
    const float* __restrict__ wgc2T, const float* __restrict__ bgc2,
    float* __restrict__ sf_all) {
  __shared__ float e_lds[Nn];
  __shared__ __align__(16) float wvT[Nn * 20];
  __shared__ float red[4][16][Hh];
  __shared__ float y2[16][Hh];
  int ig = blockIdx.x & 15;
  int tb = blockIdx.x >> 4;
  int t = tb / Bsz, b = tb % Bsz;
  int i0 = ig * 16;
  int tid = threadIdx.x, w = tid >> 6, lane = tid & 63;
  float spd = hw[(b * Tt + t) * Fw + 2];
  float rad = hw[(b * Tt + t) * Fw + 1] * DEG2RAD;
  float cr = cosf(rad), sr = sinf(rad);
  e_lds[tid] = ebuf[IDX2(t, b) * Nn + tid];
  __syncthreads();
  float ej = e_lds[tid];
#pragma unroll
  for (int r = 0; r < 16; ++r) {
    int i = i0 + r;
    int j = tid;
    float val = spd * (Ac[i * Nn + j] * cr + As[i * Nn + j] * sr);
    float wt = (j == i) ? (fmaxf(val, 0.f) * ej + ej) : (fmaxf(-val, 0.f) * ej);
    wvT[j * 20 + r] = wt;
  }
  __syncthreads();
  float acc[16];
#pragma unroll
  for (int r = 0; r < 16; ++r) acc[r] = 0.f;
  const float* h1b = h1_all + (long)IDX2(t, b) * Nn * Hh;
#pragma unroll 4
  for (int jj = 0; jj < 64; ++jj) {
    int j = w * 64 + jj;
    float hv = h1b[j * Hh + lane];
    const float4* wp = (const float4*)(wvT + j * 20);
    float4 w0 = wp[0], w1 = wp[1], w2 = wp[2], w3 = wp[3];
    acc[0] += w0.x * hv; acc[1] += w0.y * hv; acc[2] += w0.z * hv; acc[3] += w0.w * hv;
    acc[4] += w1.x * hv; acc[5] += w1.y * hv; acc[6] += w1.z * hv; acc[7] += w1.w * hv;
    acc[8] += w2.x * hv; acc[9] += w2.y * hv; acc[10] += w2.z * hv; acc[11] += w2.w * hv;
    acc[12] += w3.x * hv; acc[13] += w3.y * hv; acc[14] += w3.z * hv; acc[15] += w3.w * hv;
  }
#pragma unroll
  for (int r = 0; r < 16; ++r) red[w][r][lane] = acc[r];
  __syncthreads();
#pragma unroll
  for (int rr = 0; rr < 4; ++rr) {
    int r = w * 4 + rr;
    float v = red[0][r][lane] + red[1][r][lane] + red[2][r][lane] + red[3][r][lane];
    y2[r][lane] = v * e_lds[i0 + r];
  }
  float a0 = bgc2[lane], a1 = a0, a2 = a0, a3 = a0;
  for (int k = 0; k < Hh; ++k) {
    float wk = wgc2T[k * Hh + lane];
    a0 += wk * y2[w * 4 + 0][k];
    a1 += wk * y2[w * 4 + 1][k];
    a2 += wk * y2[w * 4 + 2][k];
    a3 += wk * y2[w * 4 + 3][k];
  }
  long base = ((long)IDX2(t, b) * Nn + i0 + w * 4) * Hh + lane;
  sf_all[base + 0 * Hh] = fmaxf(a0, 0.f);
  sf_all[base + 1 * Hh] = fmaxf(a1, 0.f);
  sf_all[base + 2 * Hh] = fmaxf(a2, 0.f);
  sf_all[base + 3 * Hh] = fmaxf(a3, 0.f);
}

// ---------------------------------------------------------------------------
// GI: gi = sf @ W_ih^T + b_ih for a chunk of TCHUNK timesteps (parallel).
// 16 rows per WAVE -> one weight pass serves 192 FMA per 4 loads. VALU-bound.
// gi layout (chunk-local): [rowc][q=0..2][lane]
// ---------------------------------------------------------------------------
__global__ __launch_bounds__(256) void k_gi(
    const float* __restrict__ sf_all, const float4* __restrict__ wihP,
    const float* __restrict__ bih, float* __restrict__ gi, int t0) {
  __shared__ float sf_c[4][16][64];
  int tid = threadIdx.x, w = tid >> 6, lane = tid & 63;
  int rowc0 = blockIdx.x * 64 + w * 16;
  long rowg0 = (long)t0 * (Bsz * Nn) + rowc0;
#pragma unroll
  for (int rr = 0; rr < 16; ++rr)
    sf_c[w][rr][lane] = sf_all[(rowg0 + rr) * Hh + lane];
  float bi_r = bih[lane], bi_z = bih[64 + lane], bi_n = bih[128 + lane];
  float ar[16], az[16], an[16];
#pragma unroll
  for (int rr = 0; rr < 16; ++rr) { ar[rr] = bi_r; az[rr] = bi_z; an[rr] = bi_n; }
#pragma unroll 2
  for (int kb = 0; kb < 16; ++kb) {
    int k0 = kb * 4;
    float4 wi0 = wihP[(k0 + 0) * 64 + lane];
    float4 wi1 = wihP[(k0 + 1) * 64 + lane];
    float4 wi2 = wihP[(k0 + 2) * 64 + lane];
    float4 wi3 = wihP[(k0 + 3) * 64 + lane];
#pragma unroll
    for (int rr = 0; rr < 16; ++rr) {
      const float4 s4 = *(const float4*)&sf_c[w][rr][k0];
      ar[rr] += s4.x * wi0.x + s4.y * wi1.x + s4.z * wi2.x + s4.w * wi3.x;
      az[rr] += s4.x * wi0.y + s4.y * wi1.y + s4.z * wi2.y + s4.w * wi3.y;
      an[rr] += s4.x * wi0.z + s4.y * wi1.z + s4.z * wi2.z + s4.w * wi3.z;
    }
  }
#pragma unroll
  for (int rr = 0; rr < 16; ++rr) {
    long rowc = rowc0 + rr;
    gi[(rowc * 3 + 0) * 64 + lane] = ar[rr];
    gi[(rowc * 3 + 1) * 64 + lane] = az[rr];
    gi[(rowc * 3 + 2) * 64 + lane] = an[rr];
  }
}

// ---------------------------------------------------------------------------
// E3 v4: GRU scan over one chunk: gh-only (half the weights/FMA of before).
// whh streamed from L1/L2; h broadcast from wave-private LDS rows; gi read
// as 3 coalesced dwords per row. No barriers in the t-loop.
// ---------------------------------------------------------------------------
__global__ __launch_bounds__(256) void k_gru_scan4(
    const float* __restrict__ gi, const float4* __restrict__ whhP,
    const float* __restrict__ bhh, float* __restrict__ hstate,
    int t0, int nt) {
  __shared__ float h_s[16][64];
  int b = blockIdx.x >> 4;
  int i0 = (blockIdx.x & 15) * 16;
  int tid = threadIdx.x, w = tid >> 6, lane = tid & 63;
  float bh_r = bhh[lane], bh_z = bhh[64 + lane], bh_n = bhh[128 + lane];
  float h_reg[4];
#pragma unroll
  for (int rr = 0; rr < 4; ++rr) {
    float hv = (t0 == 0) ? 0.f
                         : hstate[((long)b * Nn + i0 + w * 4 + rr) * Hh + lane];
    h_reg[rr] = hv;
    h_s[w * 4 + rr][lane] = hv;
  }
  for (int tl = 0; tl < nt; ++tl) {
    long rbase = ((long)tl * Bsz + b) * Nn + i0 + w * 4;
    float gr[4], gz[4], gn[4], hr[4], hz[4], hn[4];
#pragma unroll
    for (int rr = 0; rr < 4; ++rr) {
      gr[rr] = gi[((rbase + rr) * 3 + 0) * 64 + lane];
      gz[rr] = gi[((rbase + rr) * 3 + 1) * 64 + lane];
      gn[rr] = gi[((rbase + rr) * 3 + 2) * 64 + lane];
      hr[rr] = bh_r; hz[rr] = bh_z; hn[rr] = bh_n;
    }
#pragma unroll 4
    for (int kb = 0; kb < 16; ++kb) {
      int k0 = kb * 4;
      float4 wh0 = whhP[(k0 + 0) * 64 + lane];
      float4 wh1 = whhP[(k0 + 1) * 64 + lane];
      float4 wh2 = whhP[(k0 + 2) * 64 + lane];
      float4 wh3 = whhP[(k0 + 3) * 64 + lane];
#pragma unroll
      for (int rr = 0; rr < 4; ++rr) {
        const float4 h4 = *(const float4*)&h_s[w * 4 + rr][k0];
        hr[rr] += h4.x * wh0.x + h4.y * wh1.x + h4.z * wh2.x + h4.w * wh3.x;
        hz[rr] += h4.x * wh0.y + h4.y * wh1.y + h4.z * wh2.y + h4.w * wh3.y;
        hn[rr] += h4.x * wh0.z + h4.y * wh1.z + h4.z * wh2.z + h4.w * wh3.z;
      }
    }
#pragma unroll
    for (int rr = 0; rr < 4; ++rr) {
      float rg = 1.f / (1.f + expf(-(gr[rr] + hr[rr])));
      float zg = 1.f / (1.f + expf(-(gz[rr] + hz[rr])));
      float ng = tanhf(gn[rr] + rg * hn[rr]);
      float hv = (1.f - zg) * ng + zg * h_reg[rr];
      h_reg[rr] = hv;
      h_s[w * 4 + rr][lane] = hv;
    }
  }
#pragma unroll
  for (int rr = 0; rr < 4; ++rr)
    hstate[((long)b * Nn + i0 + w * 4 + rr) * Hh + lane] = h_reg[rr];
}

// ---------------------------------------------------------------------------
// D0: decoder adjacencies: AT[m][j] = A1[j][m] and A2d[i][j].
// ---------------------------------------------------------------------------
__global__ __launch_bounds__(256) void k_norm_dec(
    const float* __restrict__ hw, const float* __restrict__ Ac,
    const float* __restrict__ As,
    const float* __restrict__ dbuf, const float* __restrict__ ebuf,
    float* __restrict__ AT, float* __restrict__ A2d) {
  int b = blockIdx.x >> 8;
  int i = blockIdx.x & 255;
  int j = threadIdx.x;
  float spd = hw[(b * Tt + (Tt - 1)) * Fw + 2];
  float rad = hw[(b * Tt + (Tt - 1)) * Fw + 1] * DEG2RAD;
  float cr = cosf(rad), sr = sinf(rad);
  const float* drow = dbuf + IDX2(Tt - 1, b) * Nn;
  const float* erow = ebuf + IDX2(Tt - 1, b) * Nn;
  float val = spd * (Ac[i * Nn + j] * cr + As[i * Nn + j] * sr);
  float dlt = (j == i) ? 1.f : 0.f;
  float wtji = (j == i) ? fmaxf(val, 0.f) : fmaxf(-val, 0.f);
  AT[((long)b * Nn + i) * Nn + j]  = drow[j] * (wtji + dlt) * drow[i];
  A2d[((long)b * Nn + i) * Nn + j] = erow[i] * (wtji + dlt) * erow[j];
}

// ---------------------------------------------------------------------------
// dec0: x0 = mlp(h) for all B*N rows
// ---------------------------------------------------------------------------
__global__ __launch_bounds__(256) void k_dec0(
    const float* __restrict__ hstate,
    const float* __restrict__ wm1T, const float* __restrict__ bm1,
    const float* __restrict__ wm2T, const float* __restrict__ bm2,
    float* __restrict__ xnext) {
  const int RPB = 16;
  __shared__ float h_lds[RPB][Hh];
  __shared__ float u_lds[RPB][M1];
  int r0 = blockIdx.x * RPB;
  int tid = threadIdx.x;
#pragma unroll
  for (int c = 0; c < (RPB * Hh) / 256; ++c) {
    int idx = tid + c * 256;
    h_lds[idx >> 6][idx & 63] = hstate[(long)r0 * Hh + idx];
  }
  __syncthreads();
#pragma unroll
  for (int rep = 0; rep < 2; ++rep) {
    int idx = tid + rep * 256;
    int row = idx >> 5, m = idx & 31;
    float um = bm1[m];
    for (int k = 0; k < Hh; ++k) um += wm1T[k * M1 + m] * h_lds[row][k];
    u_lds[row][m] = fmaxf(um, 0.f);
  }
  __syncthreads();
  if (tid < RPB * Fp) {
    int row = tid / Fp, f = tid % Fp;
    float pf = bm2[f];
#pragma unroll
    for (int m = 0; m < M1; ++m) pf += wm2T[m * Fp + f] * u_lds[row][m];
    xnext[(r0 + row) * Fp + f] = pf;
  }
}

// ---------------------------------------------------------------------------
// Ddec: one self-contained kernel per decoder step (block-local full h1).
// ---------------------------------------------------------------------------
__global__ __launch_bounds__(256) void k_dec_step(
    const float* __restrict__ AT, const float* __restrict__ A2d,
    const float* __restrict__ xb_in, float* __restrict__ hstate,
    const float4* __restrict__ wihP, const float4* __restrict__ whhP,
    const float* __restrict__ wgc2T, const float* __restrict__ wgc1,
    const float* __restrict__ bgc1, const float* __restrict__ bgc2,
    const float* __restrict__ bih, const float* __restrict__ bhh,
    const float* __restrict__ wm1T, const float* __restrict__ bm1,
    const float* __restrict__ wm2T, const float* __restrict__ bm2,
    float* __restrict__ outp, float* __restrict__ xb_out, int p) {
  __shared__ float h1_s[Nn * Hh];                 // 64KB  [j][g]
  __shared__ __align__(16) float wvT[Nn * 20];    // 20KB
  __shared__ __align__(16) float scr[4096];       // 16KB
  __shared__ float y2[16][Hh];
  __shared__ float sf_s[16][Hh];
  __shared__ float h_s[16][Hh];

  int b = blockIdx.x >> 4;
  int i0 = (blockIdx.x & 15) * 16;
  int tid = threadIdx.x, w = tid >> 6, lane = tid & 63;

  for (int idx = tid; idx < Nn * Fp; idx += 256) {
    int m = idx / Fp, f = idx % Fp;
    scr[m * 8 + f] = xb_in[(long)b * Nn * Fp + idx];
  }
#pragma unroll
  for (int r = 0; r < 16; ++r)
    wvT[tid * 20 + r] = A2d[((long)b * Nn + i0 + r) * Nn + tid];
  float hp_reg[4];
#pragma unroll
  for (int rr = 0; rr < 4; ++rr) {
    hp_reg[rr] = hstate[((long)b * Nn + i0 + w * 4 + rr) * Hh + lane];
    h_s[w * 4 + rr][lane] = hp_reg[rr];
  }
  float bi_r = bih[lane], bi_z = bih[64 + lane], bi_n = bih[128 + lane];
  float bh_r = bhh[lane], bh_z = bhh[64 + lane], bh_n = bhh[128 + lane];
  float wgc1r[Fp];
#pragma unroll
  for (int f = 0; f < Fp; ++f) wgc1r[f] = wgc1[lane * Fp + f];
  float bgc1v = bgc1[lane], bgc2v = bgc2[lane];
  __syncthreads();

  // y[j = tid][f] = sum_m AT[m][j] * x[m][f]
  {
    float a0 = 0.f, a1 = 0.f, a2 = 0.f, a3 = 0.f, a4 = 0.f, a5 = 0.f;
    const float* atb = AT + (long)b * Nn * Nn;
#pragma unroll 4
    for (int m = 0; m < Nn; ++m) {
      float av = atb[m * Nn + tid];
      float4 xlo = *(const float4*)&scr[m * 8];
      float4 xhi = *(const float4*)&scr[m * 8 + 4];
      a0 += av * xlo.x; a1 += av * xlo.y; a2 += av * xlo.z;
      a3 += av * xlo.w; a4 += av * xhi.x; a5 += av * xhi.y;
    }
    __syncthreads();
    scr[2048 + tid * 8 + 0] = a0; scr[2048 + tid * 8 + 1] = a1;
    scr[2048 + tid * 8 + 2] = a2; scr[2048 + tid * 8 + 3] = a3;
    scr[2048 + tid * 8 + 4] = a4; scr[2048 + tid * 8 + 5] = a5;
  }
  __syncthreads();

  // h1_s[j][lane] = relu(Wgc1 y[j] + b)
#pragma unroll 4
  for (int jj = 0; jj < 64; ++jj) {
    int j = w * 64 + jj;
    float4 ylo = *(const float4*)&scr[2048 + j * 8];
    float4 yhi = *(const float4*)&scr[2048 + j * 8 + 4];
    float hv = bgc1v + wgc1r[0] * ylo.x + wgc1r[1] * ylo.y + wgc1r[2] * ylo.z +
               wgc1r[3] * ylo.w + wgc1r[4] * yhi.x + wgc1r[5] * yhi.y;
    h1_s[j * Hh + lane] = fmaxf(hv, 0.f);
  }
  __syncthreads();

  // aggregation z[i] = sum_j A2[i][j] h1[j]
  float acc[16];
#pragma unroll
  for (int r = 0; r < 16; ++r) acc[r] = 0.f;
#pragma unroll 4
  for (int jj = 0; jj < 64; ++jj) {
    int j = w * 64 + jj;
    float hv = h1_s[j * Hh + lane];
    const float4* wp = (const float4*)(wvT + j * 20);
    float4 w0 = wp[0], w1 = wp[1], w2 = wp[2], w3 = wp[3];
    acc[0] += w0.x * hv; acc[1] += w0.y * hv; acc[2] += w0.z * hv; acc[3] += w0.w * hv;
    acc[4] += w1.x * hv; acc[5] += w1.y * hv; acc[6] += w1.z * hv; acc[7] += w1.w * hv;
    acc[8] += w2.x * hv; acc[9] += w2.y * hv; acc[10] += w2.z * hv; acc[11] += w2.w * hv;
    acc[12] += w3.x * hv; acc[13] += w3.y * hv; acc[14] += w3.z * hv; acc[15] += w3.w * hv;
  }
  __syncthreads();
#pragma unroll
  for (int r = 0; r < 16; ++r) scr[w * 1024 + r * 64 + lane] = acc[r];
  __syncthreads();
#pragma unroll
  for (int rr = 0; rr < 4; ++rr) {
    int r = w * 4 + rr;
    y2[r][lane] = scr[r * 64 + lane] + scr[1024 + r * 64 + lane] +
                  scr[2048 + r * 64 + lane] + scr[3072 + r * 64 + lane];
  }
  // sf = relu(Wgc2 z + b2)
  {
    float a0 = bgc2v, a1 = a0, a2 = a0, a3 = a0;
    for (int k = 0; k < Hh; ++k) {
      float wk = wgc2T[k * Hh + lane];
      a0 += wk * y2[w * 4 + 0][k];
      a1 += wk * y2[w * 4 + 1][k];
      a2 += wk * y2[w * 4 + 2][k];
      a3 += wk * y2[w * 4 + 3][k];
    }
    sf_s[w * 4 + 0][lane] = fmaxf(a0, 0.f);
    sf_s[w * 4 + 1][lane] = fmaxf(a1, 0.f);
    sf_s[w * 4 + 2][lane] = fmaxf(a2, 0.f);
    sf_s[w * 4 + 3][lane] = fmaxf(a3, 0.f);
  }

  // GRU (weights streamed from global/L2)
  float hn_reg[4];
  {
    float gir[4], giz[4], gin[4], ghr[4], ghz[4], ghn[4];
#pragma unroll
    for (int rr = 0; rr < 4; ++rr) {
      gir[rr] = bi_r; giz[rr] = bi_z; gin[rr] = bi_n;
      ghr[rr] = bh_r; ghz[rr] = bh_z; ghn[rr] = bh_n;
    }
#pragma unroll 4
    for (int kb = 0; kb < 16; ++kb) {
      int k0 = kb * 4;
      float4 wi[4], wh[4];
#pragma unroll
      for (int q = 0; q < 4; ++q) {
        wi[q] = wihP[(k0 + q) * 64 + lane];
        wh[q] = whhP[(k0 + q) * 64 + lane];
      }
#pragma unroll
      for (int rr = 0; rr < 4; ++rr) {
        const float4 s4 = *(const float4*)&sf_s[w * 4 + rr][k0];
        const float4 h4 = *(const float4*)&h_s[w * 4 + rr][k0];
        gir[rr] += s4.x * wi[0].x + s4.y * wi[1].x + s4.z * wi[2].x + s4.w * wi[3].x;
        giz[rr] += s4.x * wi[0].y + s4.y * wi[1].y + s4.z * wi[2].y + s4.w * wi[3].y;
        gin[rr] += s4.x * wi[0].z + s4.y * wi[1].z + s4.z * wi[2].z + s4.w * wi[3].z;
        ghr[rr] += h4.x * wh[0].x + h4.y * wh[1].x + h4.z * wh[2].x + h4.w * wh[3].x;
        ghz[rr] += h4.x * wh[0].y + h4.y * wh[1].y + h4.z * wh[2].y + h4.w * wh[3].y;
        ghn[rr] += h4.x * wh[0].z + h4.y * wh[1].z + h4.z * wh[2].z + h4.w * wh[3].z;
      }
    }
#pragma unroll
    for (int rr = 0; rr < 4; ++rr) {
      float rg = 1.f / (1.f + expf(-(gir[rr] + ghr[rr])));
      float zg = 1.f / (1.f + expf(-(giz[rr] + ghz[rr])));
      float ng = tanhf(gin[rr] + rg * ghn[rr]);
      hn_reg[rr] = (1.f - zg) * ng + zg * hp_reg[rr];
      hstate[((long)b * Nn + i0 + w * 4 + rr) * Hh + lane] = hn_reg[rr];
    }
  }

  // MLP -> out, xb_out
  __syncthreads();
#pragma unroll
  for (int rr = 0; rr < 4; ++rr) scr[(w * 4 + rr) * 64 + lane] = hn_reg[rr];
  __syncthreads();
#pragma unroll
  for (int rep = 0; rep < 2; ++rep) {
    int idx = tid + rep * 256;
    int row = idx >> 5, m = idx & 31;
    float um = bm1[m];
    for (int k = 0; k < Hh; ++k) um += wm1T[k * M1 + m] * scr[row * 64 + k];
    scr[1024 + row * M1 + m] = fmaxf(um, 0.f);
  }
  __syncthreads();
  if (tid < 16 * Fp) {
    int row = tid / Fp, f = tid % Fp;
    float pf = bm2[f];
#pragma unroll
    for (int m = 0; m < M1; ++m) pf += wm2T[m * Fp + f] * scr[1024 + row * M1 + m];
    int i = i0 + row;
    outp[(((long)b * PredL + p) * Nn + i) * Fp + f] = pf;
    xb_out[((long)b * Nn + i) * Fp + f] = pf;
  }
}

// ---------------------------------------------------------------------------
extern "C" void kernel_launch(void* const* d_in, const int* in_sizes, int n_in,
                              void* d_out, int out_size, void* d_ws, size_t ws_size,
                              hipStream_t stream) {
  const float* hp     = (const float*)d_in[0];
  const float* hw     = (const float*)d_in[1];
  const float* adj    = (const float*)d_in[2];
  const float* coords = (const float*)d_in[3];
  const float* wgc1   = (const float*)d_in[4];
  const float* bgc1   = (const float*)d_in[5];
  const float* wgc2   = (const float*)d_in[6];
  const float* bgc2   = (const float*)d_in[7];
  const float* wih    = (const float*)d_in[8];
  const float* whh    = (const float*)d_in[9];
  const float* bih    = (const float*)d_in[10];
  const float* bhh    = (const float*)d_in[11];
  const float* wm1    = (const float*)d_in[12];
  const float* bm1    = (const float*)d_in[13];
  const float* wm2    = (const float*)d_in[14];
  const float* bm2    = (const float*)d_in[15];
  float* out = (float*)d_out;

  float* w = (float*)d_ws;
  float* Ac     = w; w += Nn * Nn;
  float* As     = w; w += Nn * Nn;
  float* dbuf   = w; w += Tt * Bsz * Nn;
  float* ebuf   = w; w += Tt * Bsz * Nn;
  float* hstate = w; w += Bsz * Nn * Hh;
  float* h1_all = w; w += (long)Tt * Bsz * Nn * Hh;
  float* sf_all = w; w += (long)Tt * Bsz * Nn * Hh;
  float* gi_ch  = w; w += (long)TCHUNK * Bsz * Nn * 3 * 64;
  float* xb0    = w; w += Bsz * Nn * Fp;
  float* xb1    = w; w += Bsz * Nn * Fp;
  float* AT     = w; w += Bsz * Nn * Nn;
  float* A2d    = w; w += Bsz * Nn * Nn;
  float* wgc2T  = w; w += Hh * Hh;
  float* wm1T   = w; w += Hh * M1;
  float* wm2T   = w; w += M1 * Fp;
  float4* wihP  = (float4*)w; w += Hh * 64 * 4;
  float4* whhP  = (float4*)w; w += Hh * 64 * 4;

  k_prep<<<Nn + 1, 256, 0, stream>>>(coords, adj, wgc2, wih, whh, wm1, wm2,
                                     Ac, As, wgc2T, wm1T, wm2T, wihP, whhP);
  k_deg<<<Tt * Bsz * 4, 256, 0, stream>>>(hw, Ac, As, dbuf, ebuf);

  k_gconv1_enc<<<Tt * Bsz * 16, 256, 0, stream>>>(hp, hw, Ac, As, dbuf,
                                                  wgc1, bgc1, h1_all);
  k_gconv2_enc<<<Tt * Bsz * 16, 256, 0, stream>>>(hw, Ac, As, ebuf, h1_all,
                                                  wgc2T, bgc2, sf_all);
  k_norm_dec<<<Bsz * Nn, 256, 0, stream>>>(hw, Ac, As, dbuf, ebuf, AT, A2d);

  for (int s = 0; s < Tt / TCHUNK; ++s) {
    int t0 = s * TCHUNK;
    k_gi<<<(TCHUNK * Bsz * Nn) / 64, 256, 0, stream>>>(sf_all, wihP, bih,
                                                       gi_ch, t0);
    k_gru_scan4<<<Bsz * 16, 256, 0, stream>>>(gi_ch, whhP, bhh, hstate,
                                              t0, TCHUNK);
  }

  k_dec0<<<Bsz * Nn / 16, 256, 0, stream>>>(hstate, wm1T, bm1, wm2T, bm2, xb0);

  for (int p = 0; p < PredL; ++p) {
    float* xin  = (p & 1) ? xb1 : xb0;
    float* xout = (p & 1) ? xb0 : xb1;
    k_dec_step<<<Bsz * 16, 256, 0, stream>>>(
        AT, A2d, xin, hstate, wihP, whhP, wgc2T, wgc1, bgc1, bgc2,
        bih, bhh, wm1T, bm1, wm2T, bm2, out, xout, p);
  }
}

// Round 6
// 738.536 us; speedup vs baseline: 1.2821x; 1.2821x over previous
//
#include <hip/hip_runtime.h>
#include <math.h>

#define Bsz 16
#define Tt 24
#define Nn 256
#define Fp 6
#define Hh 64
#define PredL 12
#define Fw 4
#define M1 32
#define TCHUNK 8
#define DEG2RAD 0.017453292519943295f
#define IDX2(t, b) ((t) * Bsz + (b))

// ---------------------------------------------------------------------------
// P0+PT: blocks 0..255 build packed pk[i][j] = {Ac,As}; block 256 repacks
// weights (wgc2T[k][g], wm1T, wm2T, wihP/whhP float4 {r,z,n,0} per [k][lane]).
// ---------------------------------------------------------------------------
__global__ __launch_bounds__(256) void k_prep(
    const float* __restrict__ coords, const float* __restrict__ adj,
    const float* __restrict__ wgc2, const float* __restrict__ wih,
    const float* __restrict__ whh,  const float* __restrict__ wm1,
    const float* __restrict__ wm2,
    float2* __restrict__ pk,
    float* __restrict__ wgc2T, float* __restrict__ wm1T, float* __restrict__ wm2T,
    float4* __restrict__ wihP, float4* __restrict__ whhP) {
  int tid = threadIdx.x;
  if (blockIdx.x < Nn) {
    int i = blockIdx.x;
    int j = tid;
    float dx = coords[2 * j]     - coords[2 * i];
    float dy = coords[2 * j + 1] - coords[2 * i + 1];
    float ang = atan2f(dy, dx);
    float a = adj[i * Nn + j];
    pk[i * Nn + j] = make_float2(a * cosf(ang), a * sinf(ang));
    return;
  }
  for (int idx = tid; idx < Hh * Hh; idx += 256) {
    int g = idx / Hh, k = idx % Hh;
    wgc2T[k * Hh + g] = wgc2[g * Hh + k];
  }
  for (int idx = tid; idx < M1 * Hh; idx += 256) {
    int m = idx / Hh, k = idx % Hh;
    wm1T[k * M1 + m] = wm1[m * Hh + k];
  }
  for (int idx = tid; idx < Fp * M1; idx += 256) {
    int f = idx / M1, m = idx % M1;
    wm2T[m * Fp + f] = wm2[f * M1 + m];
  }
  for (int idx = tid; idx < Hh * 64; idx += 256) {
    int k = idx >> 6, lane = idx & 63;
    wihP[idx] = make_float4(wih[(0 * 64 + lane) * Hh + k],
                            wih[(1 * 64 + lane) * Hh + k],
                            wih[(2 * 64 + lane) * Hh + k], 0.f);
    whhP[idx] = make_float4(whh[(0 * 64 + lane) * Hh + k],
                            whh[(1 * 64 + lane) * Hh + k],
                            whh[(2 * 64 + lane) * Hh + k], 0.f);
  }
}

// ---------------------------------------------------------------------------
// P1: degree normalizations for every (t,b,i).
// ---------------------------------------------------------------------------
__global__ __launch_bounds__(256) void k_deg(
    const float* __restrict__ hw, const float2* __restrict__ pk,
    float* __restrict__ dbuf, float* __restrict__ ebuf) {
  int q  = blockIdx.x & 3;
  int tb = blockIdx.x >> 2;
  int t = tb / Bsz, b = tb % Bsz;
  float spd = hw[(b * Tt + t) * Fw + 2];
  float rad = hw[(b * Tt + t) * Fw + 1] * DEG2RAD;
  float cr = cosf(rad), sr = sinf(rad);
  int w = threadIdx.x >> 6, lane = threadIdx.x & 63;
  for (int m = 0; m < 16; ++m) {
    int i = q * 64 + w * 16 + m;
    float rs = 0.f, cs = 0.f;
#pragma unroll
    for (int c = 0; c < 4; ++c) {
      int j = lane + 64 * c;
      float2 pv = pk[i * Nn + j];
      float val = spd * (pv.x * cr + pv.y * sr);
      rs += fmaxf(val, 0.f);
      cs += (j == i) ? fmaxf(val, 0.f) : fmaxf(-val, 0.f);
    }
#pragma unroll
    for (int off = 32; off; off >>= 1) {
      rs += __shfl_xor(rs, off);
      cs += __shfl_xor(cs, off);
    }
    if (lane == 0) {
      dbuf[IDX2(t, b) * Nn + i] = 1.f / (sqrtf(rs + 1.f) + 1e-6f);
      ebuf[IDX2(t, b) * Nn + i] = 1.f / (sqrtf(cs + 1.f) + 1e-6f);
    }
  }
}

// ---------------------------------------------------------------------------
// E12 fused: one block per (t,b); thread = row i. h1 lives only in LDS.
// Uses val(j,i) = -val(i,j) so ALL adjacency reads are pk[j*Nn+i] (coalesced).
// pass1: y = gconv1(x); h1 row -> LDS (scaled by e). pass2: z = (Win+I)e h1;
// sf = relu(W2 (e*z) + b2) -> global.
// ---------------------------------------------------------------------------
__global__ __launch_bounds__(256) void k_enc(
    const float2* __restrict__ pk, const float* __restrict__ hp,
    const float* __restrict__ hw,
    const float* __restrict__ dbuf, const float* __restrict__ ebuf,
    const float* __restrict__ wgc1, const float* __restrict__ bgc1,
    const float* __restrict__ wgc2T, const float* __restrict__ bgc2,
    float* __restrict__ sf_all) {
  __shared__ __align__(16) float u_s[Nn * 8];     // u[j][f] = d_j x[j][f]
  __shared__ __align__(16) float h1_s[Nn * 68];   // [j][68], 16 float4/row
  int tb = blockIdx.x, t = tb / Bsz, b = tb % Bsz;
  int i = threadIdx.x;
  float spd = hw[(b * Tt + t) * Fw + 2];
  float rad = hw[(b * Tt + t) * Fw + 1] * DEG2RAD;
  float cr = cosf(rad), sr = sinf(rad);
  const float* drow = dbuf + IDX2(t, b) * Nn;
  float di = drow[i];
  float ei = ebuf[IDX2(t, b) * Nn + i];
  const float* xsrc = hp + (long)(b * Tt + t) * Nn * Fp;
  for (int idx = i; idx < Nn * Fp; idx += 256) {
    int j = idx / Fp, f = idx - j * Fp;
    u_s[j * 8 + f] = drow[j] * xsrc[idx];
  }
  u_s[i * 8 + 6] = 0.f;
  u_s[i * 8 + 7] = 0.f;
  __syncthreads();

  // ---- pass 1: gconv1 aggregation (wout[i][j] = max(-val(j,i),0) offdiag) --
  float a0 = 0.f, a1 = 0.f, a2 = 0.f, a3 = 0.f, a4 = 0.f, a5 = 0.f;
#pragma unroll 4
  for (int j = 0; j < Nn; ++j) {
    float2 pv = pk[j * Nn + i];
    float vji = spd * (pv.x * cr + pv.y * sr);
    float wout = (j == i) ? fmaxf(vji, 0.f) : fmaxf(-vji, 0.f);
    float4 ul = *(const float4*)&u_s[j * 8];
    float4 uh = *(const float4*)&u_s[j * 8 + 4];
    a0 += wout * ul.x; a1 += wout * ul.y; a2 += wout * ul.z;
    a3 += wout * ul.w; a4 += wout * uh.x; a5 += wout * uh.y;
  }
  float y0 = di * (a0 + u_s[i * 8 + 0]);
  float y1 = di * (a1 + u_s[i * 8 + 1]);
  float y2v = di * (a2 + u_s[i * 8 + 2]);
  float y3 = di * (a3 + u_s[i * 8 + 3]);
  float y4 = di * (a4 + u_s[i * 8 + 4]);
  float y5 = di * (a5 + u_s[i * 8 + 5]);

  // ---- h1 row (scaled by e_i), write to LDS ----
#pragma unroll
  for (int g4 = 0; g4 < 16; ++g4) {
    float4 hv;
#pragma unroll
    for (int q = 0; q < 4; ++q) {
      int g = g4 * 4 + q;
      float v = bgc1[g] + wgc1[g * Fp + 0] * y0 + wgc1[g * Fp + 1] * y1 +
                wgc1[g * Fp + 2] * y2v + wgc1[g * Fp + 3] * y3 +
                wgc1[g * Fp + 4] * y4 + wgc1[g * Fp + 5] * y5;
      v = fmaxf(v, 0.f) * ei;
      ((float*)&hv)[q] = v;
    }
    *(float4*)&h1_s[i * 68 + g4 * 4] = hv;
  }
  __syncthreads();

  // ---- pass 2: z[i][g] = sum_j (w_in[i][j]+delta) * (e_j h1[j][g]) ----
  float z[64];
#pragma unroll
  for (int k = 0; k < 64; ++k) z[k] = 0.f;
#pragma unroll 2
  for (int j = 0; j < Nn; ++j) {
    float2 pv = pk[j * Nn + i];
    float vji = spd * (pv.x * cr + pv.y * sr);
    float wf = fmaxf(vji, 0.f) + ((j == i) ? 1.f : 0.f);
#pragma unroll
    for (int g4 = 0; g4 < 16; ++g4) {
      float4 h4 = *(const float4*)&h1_s[j * 68 + g4 * 4];
      z[g4 * 4 + 0] += wf * h4.x;
      z[g4 * 4 + 1] += wf * h4.y;
      z[g4 * 4 + 2] += wf * h4.z;
      z[g4 * 4 + 3] += wf * h4.w;
    }
  }
#pragma unroll
  for (int k = 0; k < 64; ++k) z[k] *= ei;
  __syncthreads();   // h1_s free; reuse for sf staging

  // ---- W2 transform in 4 chunks of 16 outputs (wgc2T reads are uniform) ----
#pragma unroll
  for (int c = 0; c < 4; ++c) {
    float s[16];
#pragma unroll
    for (int q = 0; q < 16; ++q) s[q] = bgc2[c * 16 + q];
#pragma unroll
    for (int k = 0; k < 64; ++k) {
      float zk = z[k];
#pragma unroll
      for (int q = 0; q < 16; ++q) s[q] += wgc2T[k * Hh + c * 16 + q] * zk;
    }
#pragma unroll
    for (int q4 = 0; q4 < 4; ++q4) {
      float4 sv = make_float4(fmaxf(s[q4 * 4 + 0], 0.f), fmaxf(s[q4 * 4 + 1], 0.f),
                              fmaxf(s[q4 * 4 + 2], 0.f), fmaxf(s[q4 * 4 + 3], 0.f));
      *(float4*)&h1_s[i * 68 + c * 16 + q4 * 4] = sv;
    }
  }
  __syncthreads();
  long base = (long)IDX2(t, b) * Nn * Hh;
  for (int idx = i; idx < Nn * 16; idx += 256) {
    int j = idx >> 4, g4 = idx & 15;
    *(float4*)&sf_all[base + j * Hh + g4 * 4] = *(const float4*)&h1_s[j * 68 + g4 * 4];
  }
}

// ---------------------------------------------------------------------------
// GI: gi = sf @ W_ih^T + b_ih for TCHUNK timesteps (16 rows/wave, VALU-bound)
// ---------------------------------------------------------------------------
__global__ __launch_bounds__(256) void k_gi(
    const float* __restrict__ sf_all, const float4* __restrict__ wihP,
    const float* __restrict__ bih, float* __restrict__ gi, int t0) {
  __shared__ float sf_c[4][16][64];
  int tid = threadIdx.x, w = tid >> 6, lane = tid & 63;
  int rowc0 = blockIdx.x * 64 + w * 16;
  long rowg0 = (long)t0 * (Bsz * Nn) + rowc0;
#pragma unroll
  for (int rr = 0; rr < 16; ++rr)
    sf_c[w][rr][lane] = sf_all[(rowg0 + rr) * Hh + lane];
  float bi_r = bih[lane], bi_z = bih[64 + lane], bi_n = bih[128 + lane];
  float ar[16], az[16], an[16];
#pragma unroll
  for (int rr = 0; rr < 16; ++rr) { ar[rr] = bi_r; az[rr] = bi_z; an[rr] = bi_n; }
#pragma unroll 2
  for (int kb = 0; kb < 16; ++kb) {
    int k0 = kb * 4;
    float4 wi0 = wihP[(k0 + 0) * 64 + lane];
    float4 wi1 = wihP[(k0 + 1) * 64 + lane];
    float4 wi2 = wihP[(k0 + 2) * 64 + lane];
    float4 wi3 = wihP[(k0 + 3) * 64 + lane];
#pragma unroll
    for (int rr = 0; rr < 16; ++rr) {
      const float4 s4 = *(const float4*)&sf_c[w][rr][k0];
      ar[rr] += s4.x * wi0.x + s4.y * wi1.x + s4.z * wi2.x + s4.w * wi3.x;
      az[rr] += s4.x * wi0.y + s4.y * wi1.y + s4.z * wi2.y + s4.w * wi3.y;
      an[rr] += s4.x * wi0.z + s4.y * wi1.z + s4.z * wi2.z + s4.w * wi3.z;
    }
  }
#pragma unroll
  for (int rr = 0; rr < 16; ++rr) {
    long rowc = rowc0 + rr;
    gi[(rowc * 3 + 0) * 64 + lane] = ar[rr];
    gi[(rowc * 3 + 1) * 64 + lane] = az[rr];
    gi[(rowc * 3 + 2) * 64 + lane] = an[rr];
  }
}

// ---------------------------------------------------------------------------
// GRU scan over one chunk (gh only; whh streamed; h broadcast via LDS rows)
// ---------------------------------------------------------------------------
__global__ __launch_bounds__(256) void k_gru_scan4(
    const float* __restrict__ gi, const float4* __restrict__ whhP,
    const float* __restrict__ bhh, float* __restrict__ hstate,
    int t0, int nt) {
  __shared__ float h_s[16][64];
  int b = blockIdx.x >> 4;
  int i0 = (blockIdx.x & 15) * 16;
  int tid = threadIdx.x, w = tid >> 6, lane = tid & 63;
  float bh_r = bhh[lane], bh_z = bhh[64 + lane], bh_n = bhh[128 + lane];
  float h_reg[4];
#pragma unroll
  for (int rr = 0; rr < 4; ++rr) {
    float hv = (t0 == 0) ? 0.f
                         : hstate[((long)b * Nn + i0 + w * 4 + rr) * Hh + lane];
    h_reg[rr] = hv;
    h_s[w * 4 + rr][lane] = hv;
  }
  for (int tl = 0; tl < nt; ++tl) {
    long rbase = ((long)tl * Bsz + b) * Nn + i0 + w * 4;
    float gr[4], gz[4], gn[4], hr[4], hz[4], hn[4];
#pragma unroll
    for (int rr = 0; rr < 4; ++rr) {
      gr[rr] = gi[((rbase + rr) * 3 + 0) * 64 + lane];
      gz[rr] = gi[((rbase + rr) * 3 + 1) * 64 + lane];
      gn[rr] = gi[((rbase + rr) * 3 + 2) * 64 + lane];
      hr[rr] = bh_r; hz[rr] = bh_z; hn[rr] = bh_n;
    }
#pragma unroll 4
    for (int kb = 0; kb < 16; ++kb) {
      int k0 = kb * 4;
      float4 wh0 = whhP[(k0 + 0) * 64 + lane];
      float4 wh1 = whhP[(k0 + 1) * 64 + lane];
      float4 wh2 = whhP[(k0 + 2) * 64 + lane];
      float4 wh3 = whhP[(k0 + 3) * 64 + lane];
#pragma unroll
      for (int rr = 0; rr < 4; ++rr) {
        const float4 h4 = *(const float4*)&h_s[w * 4 + rr][k0];
        hr[rr] += h4.x * wh0.x + h4.y * wh1.x + h4.z * wh2.x + h4.w * wh3.x;
        hz[rr] += h4.x * wh0.y + h4.y * wh1.y + h4.z * wh2.y + h4.w * wh3.y;
        hn[rr] += h4.x * wh0.z + h4.y * wh1.z + h4.z * wh2.z + h4.w * wh3.z;
      }
    }
#pragma unroll
    for (int rr = 0; rr < 4; ++rr) {
      float rg = 1.f / (1.f + expf(-(gr[rr] + hr[rr])));
      float zg = 1.f / (1.f + expf(-(gz[rr] + hz[rr])));
      float ng = tanhf(gn[rr] + rg * hn[rr]);
      float hv = (1.f - zg) * ng + zg * h_reg[rr];
      h_reg[rr] = hv;
      h_s[w * 4 + rr][lane] = hv;
    }
  }
#pragma unroll
  for (int rr = 0; rr < 4; ++rr)
    hstate[((long)b * Nn + i0 + w * 4 + rr) * Hh + lane] = h_reg[rr];
}

// ---------------------------------------------------------------------------
// D0: decoder normalized adjacencies (row layouts): A1d[i][j], A2d[i][j]
// ---------------------------------------------------------------------------
__global__ __launch_bounds__(256) void k_norm_dec(
    const float* __restrict__ hw, const float2* __restrict__ pk,
    const float* __restrict__ dbuf, const float* __restrict__ ebuf,
    float* __restrict__ A1d, float* __restrict__ A2d) {
  int b = blockIdx.x >> 8;
  int i = blockIdx.x & 255;
  int j = threadIdx.x;
  float spd = hw[(b * Tt + (Tt - 1)) * Fw + 2];
  float rad = hw[(b * Tt + (Tt - 1)) * Fw + 1] * DEG2RAD;
  float cr = cosf(rad), sr = sinf(rad);
  const float* drow = dbuf + IDX2(Tt - 1, b) * Nn;
  const float* erow = ebuf + IDX2(Tt - 1, b) * Nn;
  float2 pv = pk[i * Nn + j];
  float val = spd * (pv.x * cr + pv.y * sr);
  float dlt = (j == i) ? 1.f : 0.f;
  float wout = fmaxf(val, 0.f);
  float win  = (j == i) ? wout : fmaxf(-val, 0.f);
  A1d[((long)b * Nn + i) * Nn + j] = drow[i] * (wout + dlt) * drow[j];
  A2d[((long)b * Nn + i) * Nn + j] = erow[i] * (win + dlt) * erow[j];
}

// ---------------------------------------------------------------------------
// dec0: x0 = mlp(h) for all B*N rows
// ---------------------------------------------------------------------------
__global__ __launch_bounds__(256) void k_dec0(
    const float* __restrict__ hstate,
    const float* __restrict__ wm1T, const float* __restrict__ bm1,
    const float* __restrict__ wm2T, const float* __restrict__ bm2,
    float* __restrict__ xnext) {
  const int RPB = 16;
  __shared__ float h_lds[RPB][Hh];
  __shared__ float u_lds[RPB][M1];
  int r0 = blockIdx.x * RPB;
  int tid = threadIdx.x;
#pragma unroll
  for (int c = 0; c < (RPB * Hh) / 256; ++c) {
    int idx = tid + c * 256;
    h_lds[idx >> 6][idx & 63] = hstate[(long)r0 * Hh + idx];
  }
  __syncthreads();
#pragma unroll
  for (int rep = 0; rep < 2; ++rep) {
    int idx = tid + rep * 256;
    int row = idx >> 5, m = idx & 31;
    float um = bm1[m];
    for (int k = 0; k < Hh; ++k) um += wm1T[k * M1 + m] * h_lds[row][k];
    u_lds[row][m] = fmaxf(um, 0.f);
  }
  __syncthreads();
  if (tid < RPB * Fp) {
    int row = tid / Fp, f = tid % Fp;
    float pf = bm2[f];
#pragma unroll
    for (int m = 0; m < M1; ++m) pf += wm2T[m * Fp + f] * u_lds[row][m];
    xnext[(r0 + row) * Fp + f] = pf;
  }
}

// ---------------------------------------------------------------------------
// Ddec A: gconv1 for decoder (A1d rows, shuffle reduce) -> h1d
// ---------------------------------------------------------------------------
__global__ __launch_bounds__(256) void k_dstep_A(
    const float* __restrict__ xb, const float* __restrict__ A1d,
    const float* __restrict__ wgc1, const float* __restrict__ bgc1,
    float* __restrict__ h1d) {
  __shared__ float x_lds[Nn * Fp];
  int b = blockIdx.x >> 4;
  int i0 = (blockIdx.x & 15) * 16;
  int tid = threadIdx.x, w = tid >> 6, lane = tid & 63;
  const float* xsrc = xb + (long)b * Nn * Fp;
#pragma unroll
  for (int c = 0; c < 6; ++c) x_lds[tid + 256 * c] = xsrc[tid + 256 * c];
  __syncthreads();
#pragma unroll
  for (int rr = 0; rr < 4; ++rr) {
    int i = i0 + w * 4 + rr;
    const float* arow = A1d + ((long)b * Nn + i) * Nn;
    float acc[Fp] = {0.f, 0.f, 0.f, 0.f, 0.f, 0.f};
#pragma unroll
    for (int c = 0; c < 4; ++c) {
      int j = lane + 64 * c;
      float wt = arow[j];
#pragma unroll
      for (int f = 0; f < Fp; ++f) acc[f] += wt * x_lds[j * Fp + f];
    }
#pragma unroll
    for (int f = 0; f < Fp; ++f) {
#pragma unroll
      for (int off = 32; off; off >>= 1) acc[f] += __shfl_xor(acc[f], off);
    }
    float hv = bgc1[lane];
#pragma unroll
    for (int f = 0; f < Fp; ++f) hv += wgc1[lane * Fp + f] * acc[f];
    h1d[((long)b * Nn + i) * Hh + lane] = fmaxf(hv, 0.f);
  }
}

// ---------------------------------------------------------------------------
// Ddec B: gconv2 + W2 + GRU (streamed weights) + MLP -> out, xnext
// ---------------------------------------------------------------------------
__global__ __launch_bounds__(256) void k_dstep_B(
    const float* __restrict__ A2d, const float* __restrict__ h1d,
    const float* __restrict__ wgc2T, const float* __restrict__ bgc2,
    const float4* __restrict__ wihP, const float4* __restrict__ whhP,
    const float* __restrict__ bih, const float* __restrict__ bhh,
    float* __restrict__ hstate,
    const float* __restrict__ wm1T, const float* __restrict__ bm1,
    const float* __restrict__ wm2T, const float* __restrict__ bm2,
    float* __restrict__ outp, float* __restrict__ xnext, int p) {
  __shared__ __align__(16) float wvT[Nn * 20];
  __shared__ float red[4][16][Hh];
  __shared__ float y2[16][Hh];
  __shared__ float sf_s[16][Hh];
  __shared__ float h_s[16][Hh];
  __shared__ float hn_lds[16][Hh];
  __shared__ float u_lds[16][M1];
  int b = blockIdx.x >> 4;
  int i0 = (blockIdx.x & 15) * 16;
  int tid = threadIdx.x, w = tid >> 6, lane = tid & 63;

#pragma unroll
  for (int r = 0; r < 16; ++r)
    wvT[tid * 20 + r] = A2d[((long)b * Nn + i0 + r) * Nn + tid];
  float hp_reg[4];
#pragma unroll
  for (int rr = 0; rr < 4; ++rr) {
    hp_reg[rr] = hstate[((long)b * Nn + i0 + w * 4 + rr) * Hh + lane];
    h_s[w * 4 + rr][lane] = hp_reg[rr];
  }
  __syncthreads();

  float acc[16];
#pragma unroll
  for (int r = 0; r < 16; ++r) acc[r] = 0.f;
  const float* h1b = h1d + (long)b * Nn * Hh;
#pragma unroll 4
  for (int jj = 0; jj < 64; ++jj) {
    int j = w * 64 + jj;
    float hv = h1b[j * Hh + lane];
    const float4* wp = (const float4*)(wvT + j * 20);
    float4 w0 = wp[0], w1 = wp[1], w2 = wp[2], w3 = wp[3];
    acc[0] += w0.x * hv; acc[1] += w0.y * hv; acc[2] += w0.z * hv; acc[3] += w0.w * hv;
    acc[4] += w1.x * hv; acc[5] += w1.y * hv; acc[6] += w1.z * hv; acc[7] += w1.w * hv;
    acc[8] += w2.x * hv; acc[9] += w2.y * hv; acc[10] += w2.z * hv; acc[11] += w2.w * hv;
    acc[12] += w3.x * hv; acc[13] += w3.y * hv; acc[14] += w3.z * hv; acc[15] += w3.w * hv;
  }
#pragma unroll
  for (int r = 0; r < 16; ++r) red[w][r][lane] = acc[r];
  __syncthreads();
#pragma unroll
  for (int rr = 0; rr < 4; ++rr) {
    int r = w * 4 + rr;
    y2[r][lane] = red[0][r][lane] + red[1][r][lane] + red[2][r][lane] + red[3][r][lane];
  }
  {
    float a0 = bgc2[lane], a1 = a0, a2 = a0, a3 = a0;
    for (int k = 0; k < Hh; ++k) {
      float wk = wgc2T[k * Hh + lane];
      a0 += wk * y2[w * 4 + 0][k];
      a1 += wk * y2[w * 4 + 1][k];
      a2 += wk * y2[w * 4 + 2][k];
      a3 += wk * y2[w * 4 + 3][k];
    }
    sf_s[w * 4 + 0][lane] = fmaxf(a0, 0.f);
    sf_s[w * 4 + 1][lane] = fmaxf(a1, 0.f);
    sf_s[w * 4 + 2][lane] = fmaxf(a2, 0.f);
    sf_s[w * 4 + 3][lane] = fmaxf(a3, 0.f);
  }

  float hn_reg[4];
  {
    float bi_r = bih[lane], bi_z = bih[64 + lane], bi_n = bih[128 + lane];
    float bh_r = bhh[lane], bh_z = bhh[64 + lane], bh_n = bhh[128 + lane];
    float gir[4], giz[4], gin[4], ghr[4], ghz[4], ghn[4];
#pragma unroll
    for (int rr = 0; rr < 4; ++rr) {
      gir[rr] = bi_r; giz[rr] = bi_z; gin[rr] = bi_n;
      ghr[rr] = bh_r; ghz[rr] = bh_z; ghn[rr] = bh_n;
    }
#pragma unroll 4
    for (int kb = 0; kb < 16; ++kb) {
      int k0 = kb * 4;
      float4 wi[4], wh[4];
#pragma unroll
      for (int q = 0; q < 4; ++q) {
        wi[q] = wihP[(k0 + q) * 64 + lane];
        wh[q] = whhP[(k0 + q) * 64 + lane];
      }
#pragma unroll
      for (int rr = 0; rr < 4; ++rr) {
        const float4 s4 = *(const float4*)&sf_s[w * 4 + rr][k0];
        const float4 h4 = *(const float4*)&h_s[w * 4 + rr][k0];
        gir[rr] += s4.x * wi[0].x + s4.y * wi[1].x + s4.z * wi[2].x + s4.w * wi[3].x;
        giz[rr] += s4.x * wi[0].y + s4.y * wi[1].y + s4.z * wi[2].y + s4.w * wi[3].y;
        gin[rr] += s4.x * wi[0].z + s4.y * wi[1].z + s4.z * wi[2].z + s4.w * wi[3].z;
        ghr[rr] += h4.x * wh[0].x + h4.y * wh[1].x + h4.z * wh[2].x + h4.w * wh[3].x;
        ghz[rr] += h4.x * wh[0].y + h4.y * wh[1].y + h4.z * wh[2].y + h4.w * wh[3].y;
        ghn[rr] += h4.x * wh[0].z + h4.y * wh[1].z + h4.z * wh[2].z + h4.w * wh[3].z;
      }
    }
#pragma unroll
    for (int rr = 0; rr < 4; ++rr) {
      float rg = 1.f / (1.f + expf(-(gir[rr] + ghr[rr])));
      float zg = 1.f / (1.f + expf(-(giz[rr] + ghz[rr])));
      float ng = tanhf(gin[rr] + rg * ghn[rr]);
      hn_reg[rr] = (1.f - zg) * ng + zg * hp_reg[rr];
      hstate[((long)b * Nn + i0 + w * 4 + rr) * Hh + lane] = hn_reg[rr];
      hn_lds[w * 4 + rr][lane] = hn_reg[rr];
    }
  }
  __syncthreads();
#pragma unroll
  for (int rep = 0; rep < 2; ++rep) {
    int idx = tid + rep * 256;
    int row = idx >> 5, m = idx & 31;
    float um = bm1[m];
    for (int k = 0; k < Hh; ++k) um += wm1T[k * M1 + m] * hn_lds[row][k];
    u_lds[row][m] = fmaxf(um, 0.f);
  }
  __syncthreads();
  if (tid < 16 * Fp) {
    int row = tid / Fp, f = tid % Fp;
    float pf = bm2[f];
#pragma unroll
    for (int m = 0; m < M1; ++m) pf += wm2T[m * Fp + f] * u_lds[row][m];
    int i = i0 + row;
    outp[(((long)b * PredL + p) * Nn + i) * Fp + f] = pf;
    xnext[((long)b * Nn + i) * Fp + f] = pf;
  }
}

// ---------------------------------------------------------------------------
extern "C" void kernel_launch(void* const* d_in, const int* in_sizes, int n_in,
                              void* d_out, int out_size, void* d_ws, size_t ws_size,
                              hipStream_t stream) {
  const float* hp     = (const float*)d_in[0];
  const float* hw     = (const float*)d_in[1];
  const float* adj    = (const float*)d_in[2];
  const float* coords = (const float*)d_in[3];
  const float* wgc1   = (const float*)d_in[4];
  const float* bgc1   = (const float*)d_in[5];
  const float* wgc2   = (const float*)d_in[6];
  const float* bgc2   = (const float*)d_in[7];
  const float* wih    = (const float*)d_in[8];
  const float* whh    = (const float*)d_in[9];
  const float* bih    = (const float*)d_in[10];
  const float* bhh    = (const float*)d_in[11];
  const float* wm1    = (const float*)d_in[12];
  const float* bm1    = (const float*)d_in[13];
  const float* wm2    = (const float*)d_in[14];
  const float* bm2    = (const float*)d_in[15];
  float* out = (float*)d_out;

  float* w = (float*)d_ws;
  float2* pk    = (float2*)w; w += Nn * Nn * 2;
  float* dbuf   = w; w += Tt * Bsz * Nn;
  float* ebuf   = w; w += Tt * Bsz * Nn;
  float* hstate = w; w += Bsz * Nn * Hh;
  float* sf_all = w; w += (long)Tt * Bsz * Nn * Hh;
  float* gi_ch  = w; w += (long)TCHUNK * Bsz * Nn * 3 * 64;
  float* h1d    = w; w += Bsz * Nn * Hh;
  float* xb0    = w; w += Bsz * Nn * Fp;
  float* xb1    = w; w += Bsz * Nn * Fp;
  float* A1d    = w; w += Bsz * Nn * Nn;
  float* A2d    = w; w += Bsz * Nn * Nn;
  float* wgc2T  = w; w += Hh * Hh;
  float* wm1T   = w; w += Hh * M1;
  float* wm2T   = w; w += M1 * Fp;
  float4* wihP  = (float4*)w; w += Hh * 64 * 4;
  float4* whhP  = (float4*)w; w += Hh * 64 * 4;

  k_prep<<<Nn + 1, 256, 0, stream>>>(coords, adj, wgc2, wih, whh, wm1, wm2,
                                     pk, wgc2T, wm1T, wm2T, wihP, whhP);
  k_deg<<<Tt * Bsz * 4, 256, 0, stream>>>(hw, pk, dbuf, ebuf);

  k_enc<<<Tt * Bsz, 256, 0, stream>>>(pk, hp, hw, dbuf, ebuf,
                                      wgc1, bgc1, wgc2T, bgc2, sf_all);

  for (int s = 0; s < Tt / TCHUNK; ++s) {
    int t0 = s * TCHUNK;
    k_gi<<<(TCHUNK * Bsz * Nn) / 64, 256, 0, stream>>>(sf_all, wihP, bih,
                                                       gi_ch, t0);
    k_gru_scan4<<<Bsz * 16, 256, 0, stream>>>(gi_ch, whhP, bhh, hstate,
                                              t0, TCHUNK);
  }

  k_norm_dec<<<Bsz * Nn, 256, 0, stream>>>(hw, pk, dbuf, ebuf, A1d, A2d);
  k_dec0<<<Bsz * Nn / 16, 256, 0, stream>>>(hstate, wm1T, bm1, wm2T, bm2, xb0);

  for (int p = 0; p < PredL; ++p) {
    float* xin  = (p & 1) ? xb1 : xb0;
    float* xout = (p & 1) ? xb0 : xb1;
    k_dstep_A<<<Bsz * 16, 256, 0, stream>>>(xin, A1d, wgc1, bgc1, h1d);
    k_dstep_B<<<Bsz * 16, 256, 0, stream>>>(
        A2d, h1d, wgc2T, bgc2, wihP, whhP, bih, bhh, hstate,
        wm1T, bm1, wm2T, bm2, out, xout, p);
  }
}